// Round 7
// baseline (86.970 us; speedup 1.0000x reference)
//
#include <hip/hip_runtime.h>

// CRF loss: A=8, S=200, B=64, T=32. scores (A,S,B,T,T) f32, targets (A,S,B) i32,
// mask (S,B) bool, a_mask (A,B) bool -- bool width (u8 vs i32) runtime-detected.
// One 8-wave block per (a,b) chain; producer/consumer with double-buffered LDS
// exp-tile ring. R7: raw s_barrier (no vmcnt drain -- loads pipeline ACROSS
// barriers, compiler emits counted vmcnt before uses) + depth-2 register
// prefetch per producer wave (2 tiles in flight/wave).
constexpr int A_ = 8, S_ = 200, B_ = 64, T_ = 32;
constexpr int START_TAG = 30, END_TAG = 31;
constexpr int NW = 8;                      // waves per block = tiles per super-iter
#define LOG2E 1.44269504088896340736f
#define LN2   0.69314718055994530942f

#if __has_builtin(__builtin_amdgcn_exp2f)
#define EXP2F(x) __builtin_amdgcn_exp2f(x)
#else
#define EXP2F(x) __expf((x) * LN2)
#endif

__device__ __forceinline__ int load_flag(const void* p, bool u8, int idx) {
    return u8 ? (int)((const unsigned char*)p)[idx] : ((const int*)p)[idx];
}

// lgkmcnt(0) so our ds_writes are complete, then barrier; sched_barrier pins order.
#define BLOCK_BARRIER do {                                               \
        asm volatile("s_waitcnt lgkmcnt(0)" ::: "memory");               \
        __builtin_amdgcn_s_barrier();                                    \
        __builtin_amdgcn_sched_barrier(0);                               \
    } while (0)

__global__ __launch_bounds__(NW * 64)
void crf_loss_kernel(const float* __restrict__ scores,
                     const int* __restrict__ targets,
                     const void* __restrict__ mask,
                     const void* __restrict__ amask,
                     float* __restrict__ out)
{
    const int chain = blockIdx.x;          // 0..511
    const int a = chain >> 6;
    const int b = chain & (B_ - 1);
    const int tid = threadIdx.x;
    const int wv = tid >> 6;               // wave 0..7
    const int lane = tid & 63;
    const int t = lane & 31;
    const int fbase = (lane >> 5) << 4;    // 0 or 16

    // bool width detect: mask row 0 is all-true. int view: 1 -> int32, 0x01010101 -> uint8
    const bool bool_u8 = (((const int*)mask)[0] != 1);
    if (!load_flag(amask, bool_u8, a * B_ + b)) return;   // uniform block exit

    __shared__ __align__(16) float ebuf[2][NW][T_ * T_];  // 2 x 8 x 4KB exp-tiles
    __shared__ float gside[2][NW];                        // raw gold-path scores
    __shared__ int tg_lds[S_];
    __shared__ __align__(16) float wlds[T_];              // partition vector

    // ---- first false mask index L (prefix mask) ----
    int L = S_;
    for (int base = 0; base < S_; base += 64) {
        int i = base + lane;
        int mv = (i < S_) ? load_flag(mask, bool_u8, i * B_ + b) : 1;
        unsigned long long bal = __ballot(mv == 0);
        if (bal != 0ull && L == S_) L = base + (int)__builtin_ctzll(bal);
    }

    for (int i = tid; i < S_; i += NW * 64)
        tg_lds[i] = targets[((size_t)a * S_ + i) * B_ + b];
    __syncthreads();                        // prologue barrier (drain is fine here)

    const size_t s_stride = (size_t)B_ * T_ * T_;         // 65536 floats per step
    const float* cb = scores + ((size_t)a * S_ * B_ + b) * (T_ * T_);

    float wcur = 0.0f, C2 = 0.0f, tg = 0.0f;
    if (wv == 0) {
        wcur = EXP2F(cb[START_TAG * T_ + t] * LOG2E);
        if (lane < 32) wlds[lane] = wcur;
        tg = (L > 0) ? cb[tg_lds[0]] : 0.0f;
    }

    const int nch = (L - 1 + NW - 1) / NW;  // super-iterations (block-uniform)

#define E4(DST, SRC) do {                                                \
        DST.x = EXP2F(SRC.x * LOG2E); DST.y = EXP2F(SRC.y * LOG2E);      \
        DST.z = EXP2F(SRC.z * LOG2E); DST.w = EXP2F(SRC.w * LOG2E);      \
    } while (0)

#define RENORM do {                                                      \
        float m_ = wcur;                                                 \
        m_ = fmaxf(m_, __shfl_xor(m_, 1));                               \
        m_ = fmaxf(m_, __shfl_xor(m_, 2));                               \
        m_ = fmaxf(m_, __shfl_xor(m_, 4));                               \
        m_ = fmaxf(m_, __shfl_xor(m_, 8));                               \
        m_ = fmaxf(m_, __shfl_xor(m_, 16));                              \
        int eb_ = (__float_as_int(m_) >> 23) & 0xff;                     \
        C2 += (float)(eb_ - 127);                                        \
        float sc2_ = __int_as_float((254 - eb_) << 23);                  \
        wcur *= sc2_;                                                    \
        if (lane < 32) wlds[lane] = wcur;                                \
    } while (0)

    // Issue loads of one tile into 4 float4 regs + raw gather value.
#define TLOAD(Q0, Q1, Q2, Q3, GR, SC) do {                               \
        const int s_ = (SC);                                             \
        if (s_ < L) {                                                    \
            const float*  p_  = cb + (size_t)s_ * s_stride;              \
            const float4* p4_ = (const float4*)p_;                       \
            Q0 = p4_[lane];       Q1 = p4_[64 + lane];                   \
            Q2 = p4_[128 + lane]; Q3 = p4_[192 + lane];                  \
            GR = p_[tg_lds[s_]];                                         \
        }                                                                \
    } while (0)

    // ---- prologue prefetch: chunk 0 -> q, chunk 1 -> n ----
    float4 q0, q1, q2, q3, n0, n1, n2, n3, m0, m1, m2, m3;
    float gq = 0.0f, gn = 0.0f, gm = 0.0f;
    TLOAD(q0, q1, q2, q3, gq, 1 + wv);
    TLOAD(n0, n1, n2, n3, gn, 1 + NW + wv);

    for (int k = 0; k < nch; ++k) {
        const int scur = 1 + k * NW + wv;

        // 1) issue chunk k+2 loads (stay in flight across the barrier below)
        TLOAD(m0, m1, m2, m3, gm, scur + 2 * NW);

        // 2) exp-transform chunk k (q regs) into LDS half (k&1)
        if (scur < L) {
            float4* eb = (float4*)&ebuf[k & 1][wv][0];
            float4 e0, e1, e2, e3;
            E4(e0, q0); E4(e1, q1); E4(e2, q2); E4(e3, q3);
            eb[lane] = e0; eb[64 + lane] = e1; eb[128 + lane] = e2; eb[192 + lane] = e3;
            if (lane == 0) gside[k & 1][wv] = gq;
        }
        BLOCK_BARRIER;                      // LDS half (k&1) ready; vmcnt NOT drained

        // 3) consumer: 8 serial recursion steps from LDS (wave 0)
        if (wv == 0) {
            const int jmax = min(NW, L - 1 - k * NW);
            for (int j = 0; j < jmax; ++j) {
                const int s = 1 + k * NW + j;
                const float* eb = &ebuf[k & 1][j][0];
                float4 wa_ = *(const float4*)&wlds[fbase];
                float4 wb_ = *(const float4*)&wlds[fbase + 4];
                float4 wc_ = *(const float4*)&wlds[fbase + 8];
                float4 wd_ = *(const float4*)&wlds[fbase + 12];
                float e_[16];
#pragma unroll
                for (int i = 0; i < 16; ++i)
                    e_[i] = eb[((fbase + i) << 5) | t];
                float s0_ = fmaf(e_[3], wa_.w, fmaf(e_[2], wa_.z,
                            fmaf(e_[1], wa_.y, e_[0] * wa_.x)));
                float s1_ = fmaf(e_[7], wb_.w, fmaf(e_[6], wb_.z,
                            fmaf(e_[5], wb_.y, e_[4] * wb_.x)));
                float s2_ = fmaf(e_[11], wc_.w, fmaf(e_[10], wc_.z,
                            fmaf(e_[9], wc_.y, e_[8] * wc_.x)));
                float s3_ = fmaf(e_[15], wd_.w, fmaf(e_[14], wd_.z,
                            fmaf(e_[13], wd_.y, e_[12] * wd_.x)));
                float s_ = (s0_ + s1_) + (s2_ + s3_);
                s_ += __shfl_xor(s_, 32);
                wcur = s_;
                if (lane < 32) wlds[lane] = s_;
                tg += gside[k & 1][j];
                if ((s & 3) == 0) RENORM;
            }
        }

        // 4) rotate prefetch registers (static names, no runtime indexing)
        q0 = n0; q1 = n1; q2 = n2; q3 = n3; gq = gn;
        n0 = m0; n1 = m1; n2 = m2; n3 = m3; gn = gm;
    }

    // ---- epilogue (wave 0): logZ = ln(w[END_TAG]) + C2*ln2 ----
    if (wv == 0) {
        float wend = __shfl(wcur, END_TAG);
        float logZ = __logf(wend) + C2 * LN2;
        if (lane == 0)
            atomicAdd(out, (logZ - tg) * (1.0f / (float)B_));
    }
}

extern "C" void kernel_launch(void* const* d_in, const int* in_sizes, int n_in,
                              void* d_out, int out_size, void* d_ws, size_t ws_size,
                              hipStream_t stream) {
    const float* scores = (const float*)d_in[0];
    const int* targets  = (const int*)d_in[1];
    const void* mask    = d_in[2];
    const void* amask   = d_in[3];
    float* out = (float*)d_out;

    hipMemsetAsync(out, 0, sizeof(float), stream);
    crf_loss_kernel<<<dim3(A_ * B_), dim3(NW * 64), 0, stream>>>(
        scores, targets, mask, amask, out);
}